// Round 10
// baseline (4820.753 us; speedup 1.0000x reference)
//
#include <hip/hip_runtime.h>
#include <hip/hip_bf16.h>
#include <hip/hip_cooperative_groups.h>

// Problem dims (fixed)
#define BB 64
#define PP 196
#define ENCD 512
#define ED 1024
#define HD 1024
#define AD 512
#define VD 20000
#define TT 24
#define VPAD 20096
#define HOFF 32768 // h-part offset (shorts) inside axh

typedef __attribute__((ext_vector_type(8))) short short8;
typedef __attribute__((ext_vector_type(4))) short short4v;
typedef __attribute__((ext_vector_type(4))) float f32x4;

__device__ __forceinline__ float sigf(float x) { return 1.f / (1.f + __expf(-x)); }

__device__ __forceinline__ unsigned short f2bf(float f) {
    unsigned u = __builtin_bit_cast(unsigned, f);
    u = (u + 0x7FFFu + ((u >> 16) & 1u)) >> 16;
    return (unsigned short)u;
}
__device__ __forceinline__ void split2(float v, unsigned short& h, unsigned short& l) {
    h = f2bf(v);
    float hf = __builtin_bit_cast(float, ((unsigned)h) << 16);
    l = f2bf(v - hf);
}

// ---- hand-rolled device-scope grid barrier (sense-reversing via generation) ----
__device__ __forceinline__ void gbar(unsigned* cnt, unsigned* gen, unsigned nb) {
    __syncthreads();
    if (threadIdx.x == 0) {
        unsigned g = __hip_atomic_load(gen, __ATOMIC_RELAXED, __HIP_MEMORY_SCOPE_AGENT);
        __threadfence();   // release: my writes visible device-wide after L2 wb
        unsigned a = __hip_atomic_fetch_add(cnt, 1u, __ATOMIC_RELAXED, __HIP_MEMORY_SCOPE_AGENT);
        if (a == nb - 1) {
            __hip_atomic_store(cnt, 0u, __ATOMIC_RELAXED, __HIP_MEMORY_SCOPE_AGENT);
            __hip_atomic_store(gen, g + 1u, __ATOMIC_RELEASE, __HIP_MEMORY_SCOPE_AGENT);
        } else {
            while (__hip_atomic_load(gen, __ATOMIC_RELAXED, __HIP_MEMORY_SCOPE_AGENT) == g)
                __builtin_amdgcn_s_sleep(2);
        }
        __threadfence();   // acquire: invalidate so remote writes are visible
    }
    __syncthreads();
}

// ---- weight split ----
__global__ __launch_bounds__(256) void split_w_kernel(
    const float* __restrict__ W, unsigned short* __restrict__ oh,
    unsigned short* __restrict__ ol, int N, int Npad, int coff,
    int Nlaunch, int rowoff, int perm) {
    int n = blockIdx.x * 256 + threadIdx.x;
    if (n >= Nlaunch) return;
    int kc = blockIdx.y;
    int src = perm ? ((n & 3) * 1024 + (n >> 2)) : n;
    short8 vh, vl;
    #pragma unroll
    for (int j = 0; j < 8; ++j) {
        float v = (src < N) ? W[(size_t)(rowoff + kc * 8 + j) * N + src] : 0.f;
        unsigned short h, l; split2(v, h, l);
        vh[j] = (short)h; vl[j] = (short)l;
    }
    size_t o = ((size_t)kc * Npad + coff + n) * 8;
    *(short8*)(oh + o) = vh; *(short8*)(ol + o) = vl;
}

__global__ __launch_bounds__(256) void embed_f32_kernel(
    const int* __restrict__ captions, const float* __restrict__ table,
    float* __restrict__ emb_f) {
    int t = blockIdx.x, b = blockIdx.y;
    int tok = captions[b * 25 + t];
    const float4* src = (const float4*)(table + (size_t)tok * ED);
    float4* dst = (float4*)(emb_f + ((size_t)t * BB + b) * ED);
    dst[threadIdx.x] = src[threadIdx.x];
}

__global__ __launch_bounds__(256) void bias_perm_kernel(
    const float* __restrict__ b_ih, const float* __restrict__ b_hh,
    float* __restrict__ out) {
    int n = blockIdx.x * 256 + threadIdx.x;
    int src = (n & 3) * 1024 + (n >> 2);
    out[n] = b_ih[src] + b_hh[src];
}

__global__ __launch_bounds__(512) void mean_kernel(const float* __restrict__ enc,
                                                   float* __restrict__ mf) {
    int b = blockIdx.x; int e = threadIdx.x;
    const float* base = enc + (size_t)b * PP * ENCD + e;
    float s = 0.f;
    #pragma unroll 4
    for (int p = 0; p < PP; ++p) s += base[(size_t)p * ENCD];
    mf[b * ENCD + e] = s * (1.f / PP);
}

__global__ __launch_bounds__(256) void init_hc_kernel(
    const float* __restrict__ mf,
    const float* __restrict__ Wh, const float* __restrict__ bh,
    const float* __restrict__ Wc, const float* __restrict__ bc,
    unsigned short* __restrict__ hc_h, unsigned short* __restrict__ hc_l,
    float* __restrict__ c0) {
    int b = blockIdx.x;
    int isC = blockIdx.y;
    const float* W    = isC ? Wc : Wh;
    const float* bias = isC ? bc : bh;
    __shared__ float smf[ENCD];
    for (int i = threadIdx.x; i < ENCD; i += 256) smf[i] = mf[b * ENCD + i];
    __syncthreads();
    #pragma unroll
    for (int jj = 0; jj < 4; ++jj) {
        int j = threadIdx.x + jj * 256;
        float acc = bias[j];
        for (int k = 0; k < ENCD; ++k) acc += smf[k] * W[(size_t)k * HD + j];
        if (isC) c0[b * HD + j] = acc;
        else {
            unsigned short h, l; split2(acc, h, l);
            size_t o = ((size_t)(j >> 3) * 64 + b) * 8 + (j & 7);
            hc_h[o] = h; hc_l[o] = l;
        }
    }
}

// ---- big MFMA GEMM (unchanged, prefetched) ----
__global__ __launch_bounds__(256) void mfma_gemm_bigf(
    const float* __restrict__ Ap,
    const unsigned short* __restrict__ Bh, const unsigned short* __restrict__ Bl,
    const float* __restrict__ bias, float* __restrict__ C,
    int N, int Npad, int K, int Mtiles, int Ntiles, int inner_m) {
    __shared__ __align__(16) short lds[32768];
    short* Ahs = lds;
    short* Als = lds + 8192;
    short* Bhs = lds + 16384;
    short* Bls = lds + 24576;
    int tid = threadIdx.x, lane = tid & 63, w = tid >> 6;
    int nwg = Mtiles * Ntiles;
    int orig = blockIdx.x;
    int q = nwg >> 3, r = nwg & 7;
    int xcd = orig & 7;
    int basew = (xcd < r) ? xcd * (q + 1) : r * (q + 1) + (xcd - r) * q;
    int wg = basew + (orig >> 3);
    int mt, nt;
    if (inner_m) { mt = wg % Mtiles; nt = wg / Mtiles; }
    else         { nt = wg % Ntiles; mt = wg / Ntiles; }
    int m0 = mt * 128, n0 = nt * 128;
    int wr = w >> 1, wc = w & 1;
    f32x4 acc[4][4];
    #pragma unroll
    for (int i = 0; i < 4; ++i)
        #pragma unroll
        for (int j = 0; j < 4; ++j) acc[i][j] = (f32x4){0.f, 0.f, 0.f, 0.f};
    int nsteps = K >> 6;
    float4 va[8];
    short8 rb[2][4];
    auto load_step = [&](int s) {
        int k0 = s * 64, kc0 = s * 8;
        #pragma unroll
        for (int it = 0; it < 8; ++it) {
            int idx = it * 256 + tid; int m = idx >> 4, k4 = idx & 15;
            va[it] = *(const float4*)(Ap + (size_t)(m0 + m) * K + k0 + k4 * 4);
        }
        #pragma unroll
        for (int it = 0; it < 4; ++it) {
            int g = w * 4 + it; int kcl = g >> 1; int rb0 = (g & 1) * 64;
            size_t gb = ((size_t)(kc0 + kcl) * Npad + n0 + rb0 + lane) * 8;
            rb[0][it] = *(const short8*)(Bh + gb);
            rb[1][it] = *(const short8*)(Bl + gb);
        }
    };
    load_step(0);
    for (int s = 0; s < nsteps; ++s) {
        __syncthreads();
        #pragma unroll
        for (int it = 0; it < 8; ++it) {
            int idx = it * 256 + tid; int m = idx >> 4, k4 = idx & 15;
            int kc = k4 >> 1, jh = (k4 & 1) * 4;
            float vv[4] = {va[it].x, va[it].y, va[it].z, va[it].w};
            short4v hv, lv;
            #pragma unroll
            for (int qq = 0; qq < 4; ++qq) {
                unsigned short h, l; split2(vv[qq], h, l);
                hv[qq] = (short)h; lv[qq] = (short)l;
            }
            int o = kc * 1024 + ((m ^ kc) << 3) + jh;
            *(short4v*)(Ahs + o) = hv;
            *(short4v*)(Als + o) = lv;
        }
        #pragma unroll
        for (int it = 0; it < 4; ++it) {
            int g = w * 4 + it; int kcl = g >> 1; int rb0 = (g & 1) * 64;
            int o = (kcl * 128 + rb0 + lane) * 8;
            *(short8*)(Bhs + o) = rb[0][it];
            *(short8*)(Bls + o) = rb[1][it];
        }
        __syncthreads();
        if (s + 1 < nsteps) load_step(s + 1);
        #pragma unroll
        for (int ks = 0; ks < 2; ++ks) {
            int kq = ks * 4 + (lane >> 4);
            short8 afh[4], afl[4], bfh[4], bfl[4];
            #pragma unroll
            for (int mi = 0; mi < 4; ++mi) {
                int row = wr * 64 + mi * 16 + (lane & 15);
                int o = kq * 1024 + ((row ^ kq) << 3);
                afh[mi] = *(const short8*)(Ahs + o);
                afl[mi] = *(const short8*)(Als + o);
            }
            #pragma unroll
            for (int ni = 0; ni < 4; ++ni) {
                int o = (kq * 128 + wc * 64 + ni * 16 + (lane & 15)) * 8;
                bfh[ni] = *(const short8*)(Bhs + o);
                bfl[ni] = *(const short8*)(Bls + o);
            }
            #pragma unroll
            for (int mi = 0; mi < 4; ++mi)
                #pragma unroll
                for (int ni = 0; ni < 4; ++ni) {
                    acc[mi][ni] = __builtin_amdgcn_mfma_f32_16x16x32_bf16(afh[mi], bfh[ni], acc[mi][ni], 0, 0, 0);
                    acc[mi][ni] = __builtin_amdgcn_mfma_f32_16x16x32_bf16(afh[mi], bfl[ni], acc[mi][ni], 0, 0, 0);
                    acc[mi][ni] = __builtin_amdgcn_mfma_f32_16x16x32_bf16(afl[mi], bfh[ni], acc[mi][ni], 0, 0, 0);
                }
        }
    }
    #pragma unroll
    for (int mi = 0; mi < 4; ++mi) {
        int rrow = m0 + wr * 64 + mi * 16 + ((lane >> 4) << 2);
        #pragma unroll
        for (int ni = 0; ni < 4; ++ni) {
            int c = n0 + wc * 64 + ni * 16 + (lane & 15);
            if (c < N) {
                float bv = bias ? bias[c] : 0.f;
                #pragma unroll
                for (int qq = 0; qq < 4; ++qq)
                    C[(size_t)(rrow + qq) * N + c] = acc[mi][ni][qq] + bv;
            }
        }
    }
}

// ================== R8 step kernels (fallback path, 8-ksplit adg) ==================
__global__ __launch_bounds__(256) void hgemm_direct(
    const unsigned short* __restrict__ Ah, const unsigned short* __restrict__ Al,
    const unsigned short* __restrict__ Bh, const unsigned short* __restrict__ Bl,
    float* __restrict__ out) {
    int tid = threadIdx.x, lane = tid & 63, w = tid >> 6;
    int n0 = blockIdx.x * 128 + w * 32;
    int kc0 = blockIdx.y * 16;
    out += (size_t)blockIdx.y * 64 * 5120;
    f32x4 acc[4][2];
    #pragma unroll
    for (int i = 0; i < 4; ++i)
        #pragma unroll
        for (int j = 0; j < 2; ++j) acc[i][j] = (f32x4){0.f, 0.f, 0.f, 0.f};
    #pragma unroll
    for (int s = 0; s < 4; ++s) {
        int kc = kc0 + s * 4 + (lane >> 4);
        short8 afh[4], afl[4], bfh[2], bfl[2];
        #pragma unroll
        for (int mi = 0; mi < 4; ++mi) {
            size_t o = ((size_t)kc * 64 + mi * 16 + (lane & 15)) * 8;
            afh[mi] = *(const short8*)(Ah + o);
            afl[mi] = *(const short8*)(Al + o);
        }
        #pragma unroll
        for (int ni = 0; ni < 2; ++ni) {
            size_t o = ((size_t)kc * 5120 + n0 + ni * 16 + (lane & 15)) * 8;
            bfh[ni] = *(const short8*)(Bh + o);
            bfl[ni] = *(const short8*)(Bl + o);
        }
        #pragma unroll
        for (int mi = 0; mi < 4; ++mi)
            #pragma unroll
            for (int ni = 0; ni < 2; ++ni) {
                acc[mi][ni] = __builtin_amdgcn_mfma_f32_16x16x32_bf16(afh[mi], bfh[ni], acc[mi][ni], 0, 0, 0);
                acc[mi][ni] = __builtin_amdgcn_mfma_f32_16x16x32_bf16(afh[mi], bfl[ni], acc[mi][ni], 0, 0, 0);
                acc[mi][ni] = __builtin_amdgcn_mfma_f32_16x16x32_bf16(afl[mi], bfh[ni], acc[mi][ni], 0, 0, 0);
            }
    }
    #pragma unroll
    for (int mi = 0; mi < 4; ++mi) {
        int rrow = mi * 16 + ((lane >> 4) << 2);
        #pragma unroll
        for (int ni = 0; ni < 2; ++ni) {
            int c = n0 + ni * 16 + (lane & 15);
            #pragma unroll
            for (int qq = 0; qq < 4; ++qq)
                out[(size_t)(rrow + qq) * 5120 + c] = acc[mi][ni][qq];
        }
    }
}

__global__ __launch_bounds__(1024) void attn_ctx_kernel(
    const float* __restrict__ att_enc, const float* __restrict__ adg,
    const float* __restrict__ b_dec, const float* __restrict__ Wfull,
    const float* __restrict__ enc, const float* __restrict__ b_fbeta,
    float* __restrict__ alpha_out, unsigned short* __restrict__ x2h,
    unsigned short* __restrict__ x2l, int t) {
    int b = blockIdx.x; int tid = threadIdx.x;
    __shared__ float sdec[AD], sw[AD], sgate[AD], sal[256], sE[256], red[256];
    __shared__ float sctx[2][AD];
    if (tid < AD) {
        float s = b_dec[tid];
        #pragma unroll
        for (int ks = 0; ks < 8; ++ks) s += adg[((size_t)ks * BB + b) * 5120 + tid];
        sdec[tid] = s;
        sw[tid] = Wfull[tid];
    } else {
        int e = tid - AD;
        float s = b_fbeta[e];
        #pragma unroll
        for (int ks = 0; ks < 8; ++ks) s += adg[((size_t)ks * BB + b) * 5120 + 512 + e];
        sgate[e] = s;
    }
    __syncthreads();
    int w = tid >> 6, lane = tid & 63;
    float4 sd0 = *(const float4*)&sdec[lane * 8];
    float4 sd1 = *(const float4*)&sdec[lane * 8 + 4];
    float4 sw0 = *(const float4*)&sw[lane * 8];
    float4 sw1 = *(const float4*)&sw[lane * 8 + 4];
    for (int p = w; p < PP; p += 16) {
        const float* row = att_enc + ((size_t)b * PP + p) * AD + lane * 8;
        float4 v0 = *(const float4*)row;
        float4 v1 = *(const float4*)(row + 4);
        float part = fmaxf(v0.x + sd0.x, 0.f) * sw0.x + fmaxf(v0.y + sd0.y, 0.f) * sw0.y +
                     fmaxf(v0.z + sd0.z, 0.f) * sw0.z + fmaxf(v0.w + sd0.w, 0.f) * sw0.w +
                     fmaxf(v1.x + sd1.x, 0.f) * sw1.x + fmaxf(v1.y + sd1.y, 0.f) * sw1.y +
                     fmaxf(v1.z + sd1.z, 0.f) * sw1.z + fmaxf(v1.w + sd1.w, 0.f) * sw1.w;
        #pragma unroll
        for (int off = 32; off > 0; off >>= 1) part += __shfl_down(part, off, 64);
        if (lane == 0) sE[p] = part;
    }
    __syncthreads();
    float myE = (tid < PP) ? sE[tid] : -1e30f;
    if (tid < 256) red[tid] = myE;
    __syncthreads();
    for (int s = 128; s > 0; s >>= 1) {
        if (tid < s) red[tid] = fmaxf(red[tid], red[tid + s]);
        __syncthreads();
    }
    float mx = red[0];
    __syncthreads();
    float ex = (tid < PP) ? __expf(myE - mx) : 0.f;
    if (tid < 256) red[tid] = ex;
    __syncthreads();
    for (int s = 128; s > 0; s >>= 1) {
        if (tid < s) red[tid] += red[tid + s];
        __syncthreads();
    }
    if (tid < PP) {
        float al = ex * (1.f / red[0]);
        sal[tid] = al;
        alpha_out[((size_t)b * TT + t) * PP + tid] = al;
    }
    __syncthreads();
    int e = tid & 511, half = tid >> 9;
    const float* basep = enc + (size_t)b * PP * ENCD + e;
    float s2 = 0.f;
    #pragma unroll 2
    for (int p = half * 98; p < half * 98 + 98; ++p) s2 += sal[p] * basep[(size_t)p * ENCD];
    sctx[half][e] = s2;
    __syncthreads();
    if (tid < AD) {
        float ctx = sctx[0][tid] + sctx[1][tid];
        float gate = sigf(sgate[tid]);
        unsigned short h, l; split2(gate * ctx, h, l);
        size_t o = ((size_t)(tid >> 3) * 64 + b) * 8 + (tid & 7);
        x2h[o] = h; x2l[o] = l;
    }
}

__global__ __launch_bounds__(256) void gates_lstm2(
    const unsigned short* __restrict__ Ah, const unsigned short* __restrict__ Al,
    const unsigned short* __restrict__ Bh, const unsigned short* __restrict__ Bl,
    const float* __restrict__ pregates, const float* __restrict__ adg,
    float* __restrict__ c, unsigned short* __restrict__ ho_h,
    unsigned short* __restrict__ ho_l, float* __restrict__ h_all, int t) {
    __shared__ float gl[4][64][33];
    int tid = threadIdx.x, lane = tid & 63, w = tid >> 6;
    int n0 = blockIdx.x * 32;
    f32x4 acc[4][2];
    #pragma unroll
    for (int i = 0; i < 4; ++i)
        #pragma unroll
        for (int j = 0; j < 2; ++j) acc[i][j] = (f32x4){0.f, 0.f, 0.f, 0.f};
    #pragma unroll
    for (int s = 0; s < 4; ++s) {
        int kc = w * 16 + s * 4 + (lane >> 4);
        short8 afh[4], afl[4], bfh[2], bfl[2];
        #pragma unroll
        for (int mi = 0; mi < 4; ++mi) {
            size_t o = ((size_t)kc * 64 + mi * 16 + (lane & 15)) * 8;
            afh[mi] = *(const short8*)(Ah + o);
            afl[mi] = *(const short8*)(Al + o);
        }
        #pragma unroll
        for (int ni = 0; ni < 2; ++ni) {
            size_t o = ((size_t)kc * 4096 + n0 + ni * 16 + (lane & 15)) * 8;
            bfh[ni] = *(const short8*)(Bh + o);
            bfl[ni] = *(const short8*)(Bl + o);
        }
        #pragma unroll
        for (int mi = 0; mi < 4; ++mi)
            #pragma unroll
            for (int ni = 0; ni < 2; ++ni) {
                acc[mi][ni] = __builtin_amdgcn_mfma_f32_16x16x32_bf16(afh[mi], bfh[ni], acc[mi][ni], 0, 0, 0);
                acc[mi][ni] = __builtin_amdgcn_mfma_f32_16x16x32_bf16(afh[mi], bfl[ni], acc[mi][ni], 0, 0, 0);
                acc[mi][ni] = __builtin_amdgcn_mfma_f32_16x16x32_bf16(afl[mi], bfh[ni], acc[mi][ni], 0, 0, 0);
            }
    }
    #pragma unroll
    for (int mi = 0; mi < 4; ++mi) {
        int rrow = mi * 16 + ((lane >> 4) << 2);
        #pragma unroll
        for (int ni = 0; ni < 2; ++ni) {
            int cl = ni * 16 + (lane & 15);
            #pragma unroll
            for (int qq = 0; qq < 4; ++qq)
                gl[w][rrow + qq][cl] = acc[mi][ni][qq];
        }
    }
    __syncthreads();
    #pragma unroll
    for (int i = 0; i < 2; ++i) {
        int idx = tid + i * 256;
        int b = idx >> 3, jl = idx & 7;
        float g4[4];
        #pragma unroll
        for (int qq = 0; qq < 4; ++qq)
            g4[qq] = gl[0][b][4 * jl + qq] + gl[1][b][4 * jl + qq] +
                     gl[2][b][4 * jl + qq] + gl[3][b][4 * jl + qq];
        {
            float4 pv = *(const float4*)&pregates[((size_t)(t * 64 + b)) * 4096 + n0 + 4 * jl];
            g4[0] += pv.x; g4[1] += pv.y; g4[2] += pv.z; g4[3] += pv.w;
        }
        #pragma unroll
        for (int ks = 0; ks < 8; ++ks) {
            float4 av = *(const float4*)&adg[((size_t)ks * BB + b) * 5120 + 1024 + n0 + 4 * jl];
            g4[0] += av.x; g4[1] += av.y; g4[2] += av.z; g4[3] += av.w;
        }
        int j = (n0 >> 2) + jl;
        float cn = sigf(g4[1]) * c[b * HD + j] + sigf(g4[0]) * tanhf(g4[2]);
        c[b * HD + j] = cn;
        float hn = sigf(g4[3]) * tanhf(cn);
        unsigned short h, l; split2(hn, h, l);
        size_t o1 = ((size_t)(j >> 3) * 64 + b) * 8 + (j & 7);
        ho_h[o1] = h; ho_l[o1] = l;
        h_all[((size_t)b * TT + t) * HD + j] = hn;
    }
}

// ================== R10: persistent step loop, hand-rolled barrier ==================
// 256 blocks x 256 threads (4 waves). 3 barriers/step. adg uses 4 K-splits.
__global__ __launch_bounds__(256, 1) void step_kernel(
    unsigned short* axh_h0, unsigned short* axh_l0,
    unsigned short* axh_h1, unsigned short* axh_l1,
    const unsigned short* __restrict__ wbig_h, const unsigned short* __restrict__ wbig_l,
    const unsigned short* __restrict__ wih2_h, const unsigned short* __restrict__ wih2_l,
    const float* __restrict__ att_enc, const float* __restrict__ enc,
    const float* __restrict__ b_dec, const float* __restrict__ Wfull,
    const float* __restrict__ b_fbeta, const float* __restrict__ pregates,
    float* __restrict__ adg, float* __restrict__ c_buf,
    float* __restrict__ alphas, float* __restrict__ h_all,
    unsigned* __restrict__ bar) {
    __shared__ __align__(16) float smem[4 * 64 * 17];   // 17.4 KB, phase-overlaid
    unsigned short* axh_h[2] = {axh_h0, axh_h1};
    unsigned short* axh_l[2] = {axh_l0, axh_l1};
    unsigned* cnt = bar;
    unsigned* gen = bar + 32;   // separate cachelines
    int bid = blockIdx.x, tid = threadIdx.x, lane = tid & 63, w = tid >> 6;
    const unsigned NB = 256;

    for (int t = 0; t < TT; ++t) {
        int par = t & 1;
        const unsigned short* hh = axh_h[par] + HOFF;
        const unsigned short* hl = axh_l[par] + HOFF;
        // ---- Phase A: adg[4][64][5120] = h @ Wbig. 640 wave-units on 1024 waves. ----
        {
            int gw = bid * 4 + w;
            if (gw < 640) {
                int ct = gw % 160, ks = gw / 160;
                int n0 = ct * 32, kc0 = ks * 32;
                f32x4 acc[4][2];
                #pragma unroll
                for (int i = 0; i < 4; ++i)
                    #pragma unroll
                    for (int j = 0; j < 2; ++j) acc[i][j] = (f32x4){0.f, 0.f, 0.f, 0.f};
                #pragma unroll
                for (int s = 0; s < 8; ++s) {
                    int kc = kc0 + s * 4 + (lane >> 4);
                    short8 afh[4], afl[4], bfh[2], bfl[2];
                    #pragma unroll
                    for (int mi = 0; mi < 4; ++mi) {
                        size_t o = ((size_t)kc * 64 + mi * 16 + (lane & 15)) * 8;
                        afh[mi] = *(const short8*)(hh + o);
                        afl[mi] = *(const short8*)(hl + o);
                    }
                    #pragma unroll
                    for (int ni = 0; ni < 2; ++ni) {
                        size_t o = ((size_t)kc * 5120 + n0 + ni * 16 + (lane & 15)) * 8;
                        bfh[ni] = *(const short8*)(wbig_h + o);
                        bfl[ni] = *(const short8*)(wbig_l + o);
                    }
                    #pragma unroll
                    for (int mi = 0; mi < 4; ++mi)
                        #pragma unroll
                        for (int ni = 0; ni < 2; ++ni) {
                            acc[mi][ni] = __builtin_amdgcn_mfma_f32_16x16x32_bf16(afh[mi], bfh[ni], acc[mi][ni], 0, 0, 0);
                            acc[mi][ni] = __builtin_amdgcn_mfma_f32_16x16x32_bf16(afh[mi], bfl[ni], acc[mi][ni], 0, 0, 0);
                            acc[mi][ni] = __builtin_amdgcn_mfma_f32_16x16x32_bf16(afl[mi], bfh[ni], acc[mi][ni], 0, 0, 0);
                        }
                }
                float* op = adg + (size_t)ks * 64 * 5120;
                #pragma unroll
                for (int mi = 0; mi < 4; ++mi) {
                    int rrow = mi * 16 + ((lane >> 4) << 2);
                    #pragma unroll
                    for (int ni = 0; ni < 2; ++ni) {
                        int cc = n0 + ni * 16 + (lane & 15);
                        #pragma unroll
                        for (int qq = 0; qq < 4; ++qq)
                            op[(size_t)(rrow + qq) * 5120 + cc] = acc[mi][ni][qq];
                    }
                }
            }
        }
        gbar(cnt, gen, NB);
        // ---- Phase B: full attention for batch b = bid (bid < 64). ----
        if (bid < BB) {
            int b = bid;
            float* sdec = smem;          // 512
            float* sw   = smem + 512;    // 512
            float* sE   = smem + 1024;   // 256
            float* red  = smem + 1280;   // 256
            float* sal  = smem + 1536;   // 256
            for (int i = tid; i < AD; i += 256) {
                float s = b_dec[i];
                #pragma unroll
                for (int ks = 0; ks < 4; ++ks) s += adg[((size_t)ks * BB + b) * 5120 + i];
                sdec[i] = s;
                sw[i] = Wfull[i];
            }
            __syncthreads();
            float4 sd0 = *(const float4*)&sdec[lane * 8];
            float4 sd1 = *(const float4*)&sdec[lane * 8 + 4];
            float4 sw0 = *(const float4*)&sw[lane * 8];
            float4 sw1 = *(const float4*)&sw[lane * 8 + 4];
            for (int p = w; p < PP; p += 4) {
                const float* row = att_enc + ((size_t)b * PP + p) * AD + lane * 8;
                float4 v0 = *(const float4*)row;
                float4 v1 = *(const float4*)(row + 4);
                float part = fmaxf(v0.x + sd0.x, 0.f) * sw0.x + fmaxf(v0.y + sd0.y, 0.f) * sw0.y +
                             fmaxf(v0.z + sd0.z, 0.f) * sw0.z + fmaxf(v0.w + sd0.w, 0.f) * sw0.w +
                             fmaxf(v1.x + sd1.x, 0.f) * sw1.x + fmaxf(v1.y + sd1.y, 0.f) * sw1.y +
                             fmaxf(v1.z + sd1.z, 0.f) * sw1.z + fmaxf(v1.w + sd1.w, 0.f) * sw1.w;
                #pragma unroll
                for (int off = 32; off > 0; off >>= 1) part += __shfl_down(part, off, 64);
                if (lane == 0) sE[p] = part;
            }
            __syncthreads();
            float myE = (tid < PP) ? sE[tid] : -1e30f;
            red[tid] = myE;
            __syncthreads();
            for (int s = 128; s > 0; s >>= 1) {
                if (tid < s) red[tid] = fmaxf(red[tid], red[tid + s]);
                __syncthreads();
            }
            float mx = red[0];
            __syncthreads();
            float ex = (tid < PP) ? __expf(myE - mx) : 0.f;
            red[tid] = ex;
            __syncthreads();
            for (int s = 128; s > 0; s >>= 1) {
                if (tid < s) red[tid] += red[tid + s];
                __syncthreads();
            }
            if (tid < PP) {
                float al = ex * (1.f / red[0]);
                sal[tid] = al;
                alphas[((size_t)b * TT + t) * PP + tid] = al;
            }
            __syncthreads();
            #pragma unroll
            for (int rep = 0; rep < 2; ++rep) {
                int e = tid + rep * 256;
                const float* basep = enc + (size_t)b * PP * ENCD + e;
                float s2 = 0.f;
                #pragma unroll 2
                for (int p = 0; p < PP; ++p) s2 += sal[p] * basep[(size_t)p * ENCD];
                float gpre = b_fbeta[e];
                #pragma unroll
                for (int ks = 0; ks < 4; ++ks)
                    gpre += adg[((size_t)ks * BB + b) * 5120 + 512 + e];
                float gate = sigf(gpre);
                unsigned short h, l; split2(gate * s2, h, l);
                size_t o = ((size_t)(e >> 3) * 64 + b) * 8 + (e & 7);
                axh_h[par][o] = h; axh_l[par][o] = l;
            }
        }
        gbar(cnt, gen, NB);
        // ---- Phase C: gates = x2 @ Wih2 (K=512, 4-wave split) + partials -> LSTM ----
        {
            float (*gl)[64][17] = (float(*)[64][17])smem;
            const unsigned short* xh = axh_h[par];
            const unsigned short* xl = axh_l[par];
            int n0 = bid * 16;
            f32x4 acc[4];
            #pragma unroll
            for (int i = 0; i < 4; ++i) acc[i] = (f32x4){0.f, 0.f, 0.f, 0.f};
            #pragma unroll
            for (int s = 0; s < 4; ++s) {
                int kc = w * 16 + s * 4 + (lane >> 4);
                short8 afh[4], afl[4], bfh, bfl;
                #pragma unroll
                for (int mi = 0; mi < 4; ++mi) {
                    size_t o = ((size_t)kc * 64 + mi * 16 + (lane & 15)) * 8;
                    afh[mi] = *(const short8*)(xh + o);
                    afl[mi] = *(const short8*)(xl + o);
                }
                size_t ob = ((size_t)kc * 4096 + n0 + (lane & 15)) * 8;
                bfh = *(const short8*)(wih2_h + ob);
                bfl = *(const short8*)(wih2_l + ob);
                #pragma unroll
                for (int mi = 0; mi < 4; ++mi) {
                    acc[mi] = __builtin_amdgcn_mfma_f32_16x16x32_bf16(afh[mi], bfh, acc[mi], 0, 0, 0);
                    acc[mi] = __builtin_amdgcn_mfma_f32_16x16x32_bf16(afh[mi], bfl, acc[mi], 0, 0, 0);
                    acc[mi] = __builtin_amdgcn_mfma_f32_16x16x32_bf16(afl[mi], bfh, acc[mi], 0, 0, 0);
                }
            }
            __syncthreads();   // smem handoff from phase B layout
            #pragma unroll
            for (int mi = 0; mi < 4; ++mi) {
                int rrow = mi * 16 + ((lane >> 4) << 2);
                int cl = lane & 15;
                #pragma unroll
                for (int qq = 0; qq < 4; ++qq)
                    gl[w][rrow + qq][cl] = acc[mi][qq];
            }
            __syncthreads();
            int b = tid >> 2, jl = tid & 3;
            float g4[4];
            #pragma unroll
            for (int qq = 0; qq < 4; ++qq)
                g4[qq] = gl[0][b][4 * jl + qq] + gl[1][b][4 * jl + qq] +
                         gl[2][b][4 * jl + qq] + gl[3][b][4 * jl + qq];
            {
                float4 pv = *(const float4*)&pregates[((size_t)(t * 64 + b)) * 4096 + n0 + 4 * jl];
                g4[0] += pv.x; g4[1] += pv.y; g4[2] += pv.z; g4[3] += pv.w;
            }
            #pragma unroll
            for (int ks = 0; ks < 4; ++ks) {
                float4 av = *(const float4*)&adg[((size_t)ks * BB + b) * 5120 + 1024 + n0 + 4 * jl];
                g4[0] += av.x; g4[1] += av.y; g4[2] += av.z; g4[3] += av.w;
            }
            int j = bid * 4 + jl;
            float cn = sigf(g4[1]) * c_buf[b * HD + j] + sigf(g4[0]) * tanhf(g4[2]);
            c_buf[b * HD + j] = cn;
            float hn = sigf(g4[3]) * tanhf(cn);
            unsigned short h, l; split2(hn, h, l);
            size_t o1 = ((size_t)(j >> 3) * 64 + b) * 8 + (j & 7);
            unsigned short* oh = axh_h[1 - par] + HOFF;
            unsigned short* ol = axh_l[1 - par] + HOFF;
            oh[o1] = h; ol[o1] = l;
            h_all[((size_t)b * TT + t) * HD + j] = hn;
            __syncthreads();   // protect smem before next step's phase B
        }
        gbar(cnt, gen, NB);
    }
}

extern "C" void kernel_launch(void* const* d_in, const int* in_sizes, int n_in,
                              void* d_out, int out_size, void* d_ws, size_t ws_size,
                              hipStream_t stream) {
    const float* enc      = (const float*)d_in[0];
    const int*   captions = (const int*)d_in[1];
    const float* W_enc    = (const float*)d_in[3];
    const float* b_enc    = (const float*)d_in[4];
    const float* W_dec    = (const float*)d_in[5];
    const float* b_dec    = (const float*)d_in[6];
    const float* W_full   = (const float*)d_in[7];
    const float* table    = (const float*)d_in[9];
    const float* W_ih     = (const float*)d_in[10];
    const float* b_ih     = (const float*)d_in[11];
    const float* W_hh     = (const float*)d_in[12];
    const float* b_hh     = (const float*)d_in[13];
    const float* W_init_h = (const float*)d_in[14];
    const float* b_init_h = (const float*)d_in[15];
    const float* W_init_c = (const float*)d_in[16];
    const float* b_init_c = (const float*)d_in[17];
    const float* W_fbeta  = (const float*)d_in[18];
    const float* b_fbeta  = (const float*)d_in[19];
    const float* W_fc     = (const float*)d_in[20];
    const float* b_fc     = (const float*)d_in[21];

    float* preds  = (float*)d_out;
    float* alphas = (float*)d_out + (size_t)BB * TT * VD;

    char* base = (char*)d_ws;
    size_t off = 0;
    auto take = [&](size_t b) { void* r = (void*)(base + off); off += (b + 255) & ~(size_t)255; return r; };
    float* att_enc = (float*)take((size_t)12544 * 512 * 4);
    unsigned short* wbig_h = (unsigned short*)take((size_t)128 * 5120 * 8 * 2);
    unsigned short* wbig_l = (unsigned short*)take((size_t)128 * 5120 * 8 * 2);
    unsigned short* wih1_h = (unsigned short*)take((size_t)128 * 4096 * 8 * 2);
    unsigned short* wih1_l = (unsigned short*)take((size_t)128 * 4096 * 8 * 2);
    unsigned short* wih2_h = (unsigned short*)take((size_t)64 * 4096 * 8 * 2);
    unsigned short* wih2_l = (unsigned short*)take((size_t)64 * 4096 * 8 * 2);
    unsigned short* wenc_h = (unsigned short*)take((size_t)64 * 512 * 8 * 2);
    unsigned short* wenc_l = (unsigned short*)take((size_t)64 * 512 * 8 * 2);
    float* pregates = (float*)take((size_t)TT * BB * 4096 * 4);
    float* adg      = (float*)take((size_t)8 * BB * 5120 * 4);   // 8-split sized (fallback); coop uses first 4
    float* emb_f    = adg;   // aliases adg (dead before loop)
    float* biasp    = (float*)take((size_t)4096 * 4);
    unsigned short* wfc_h = (unsigned short*)(base);
    unsigned short* wfc_l = (unsigned short*)(base + (size_t)128 * VPAD * 8 * 2);
    float* c_buf = (float*)take((size_t)BB * HD * 4);
    float* mf    = (float*)take((size_t)BB * ENCD * 4);
    unsigned short* axh_h0 = (unsigned short*)take((size_t)192 * 64 * 8 * 2);
    unsigned short* axh_l0 = (unsigned short*)take((size_t)192 * 64 * 8 * 2);
    unsigned short* axh_h1 = (unsigned short*)take((size_t)192 * 64 * 8 * 2);
    unsigned short* axh_l1 = (unsigned short*)take((size_t)192 * 64 * 8 * 2);
    float* h_all = (float*)take((size_t)TT * BB * HD * 4);
    unsigned* bar = (unsigned*)take(256);   // cnt @ +0, gen @ +32 (words)

    // ---- prologue ----
    hipMemsetAsync(bar, 0, 256, stream);
    split_w_kernel<<<dim3(2, 64), 256, 0, stream>>>(W_enc, wenc_h, wenc_l, 512, 512, 0, 512, 0, 0);
    split_w_kernel<<<dim3(2, 128), 256, 0, stream>>>(W_dec, wbig_h, wbig_l, 512, 5120, 0, 512, 0, 0);
    split_w_kernel<<<dim3(2, 128), 256, 0, stream>>>(W_fbeta, wbig_h, wbig_l, 512, 5120, 512, 512, 0, 0);
    split_w_kernel<<<dim3(16, 128), 256, 0, stream>>>(W_hh, wbig_h, wbig_l, 4096, 5120, 1024, 4096, 0, 1);
    split_w_kernel<<<dim3(16, 128), 256, 0, stream>>>(W_ih, wih1_h, wih1_l, 4096, 4096, 0, 4096, 0, 1);
    split_w_kernel<<<dim3(16, 64), 256, 0, stream>>>(W_ih, wih2_h, wih2_l, 4096, 4096, 0, 4096, 1024, 1);
    bias_perm_kernel<<<16, 256, 0, stream>>>(b_ih, b_hh, biasp);
    embed_f32_kernel<<<dim3(TT, BB), 256, 0, stream>>>(captions, table, emb_f);
    mean_kernel<<<BB, 512, 0, stream>>>(enc, mf);
    init_hc_kernel<<<dim3(BB, 2), 256, 0, stream>>>(mf, W_init_h, b_init_h, W_init_c, b_init_c,
                                                    axh_h0 + HOFF, axh_l0 + HOFF, c_buf);
    mfma_gemm_bigf<<<392, 256, 0, stream>>>(enc, wenc_h, wenc_l, b_enc, att_enc,
                                            512, 512, 512, 98, 4, 0);
    mfma_gemm_bigf<<<384, 256, 0, stream>>>(emb_f, wih1_h, wih1_l, biasp, pregates,
                                            4096, 4096, 1024, 12, 32, 1);

    // ---- persistent step loop with hand-rolled barrier (fallback: R8 loop) ----
    {
        const float* enc_a = enc; const float* bdec_a = b_dec; const float* wfull_a = W_full;
        const float* bfb_a = b_fbeta;
        void* args[] = {
            (void*)&axh_h0, (void*)&axh_l0, (void*)&axh_h1, (void*)&axh_l1,
            (void*)&wbig_h, (void*)&wbig_l, (void*)&wih2_h, (void*)&wih2_l,
            (void*)&att_enc, (void*)&enc_a, (void*)&bdec_a, (void*)&wfull_a,
            (void*)&bfb_a, (void*)&pregates, (void*)&adg, (void*)&c_buf,
            (void*)&alphas, (void*)&h_all, (void*)&bar
        };
        hipError_t cerr = hipLaunchCooperativeKernel((const void*)step_kernel,
                                                     dim3(256), dim3(256), args, 0, stream);
        if (cerr != hipSuccess) {
            unsigned short* ah[2] = {axh_h0, axh_h1};
            unsigned short* al[2] = {axh_l0, axh_l1};
            for (int t = 0; t < TT; ++t) {
                int par = t & 1;
                hgemm_direct<<<dim3(40, 8), 256, 0, stream>>>(
                    ah[par] + HOFF, al[par] + HOFF, wbig_h, wbig_l, adg);
                attn_ctx_kernel<<<BB, 1024, 0, stream>>>(att_enc, adg, b_dec, W_full, enc,
                                                         b_fbeta, alphas, ah[par], al[par], t);
                gates_lstm2<<<128, 256, 0, stream>>>(
                    ah[par], al[par], wih2_h, wih2_l, pregates, adg, c_buf,
                    ah[1 - par] + HOFF, al[1 - par] + HOFF, h_all, t);
            }
        }
    }

    // ---- epilogue ----
    split_w_kernel<<<dim3(79, 128), 256, 0, stream>>>(W_fc, wfc_h, wfc_l, VD, VPAD, 0, VPAD, 0, 0);
    mfma_gemm_bigf<<<1884, 256, 0, stream>>>(h_all, wfc_h, wfc_l, b_fc, preds,
                                             VD, VPAD, 1024, 12, 157, 1);
}

// Round 11
// 1525.083 us; speedup vs baseline: 3.1610x; 3.1610x over previous
//
#include <hip/hip_runtime.h>
#include <hip/hip_bf16.h>

// Problem dims (fixed)
#define BB 64
#define PP 196
#define ENCD 512
#define ED 1024
#define HD 1024
#define AD 512
#define VD 20000
#define TT 24
#define VPAD 20096
#define HOFF 32768 // h-part offset (shorts) inside axh

typedef __attribute__((ext_vector_type(8))) short short8;
typedef __attribute__((ext_vector_type(4))) short short4v;
typedef __attribute__((ext_vector_type(4))) float f32x4;

__device__ __forceinline__ float sigf(float x) { return 1.f / (1.f + __expf(-x)); }

__device__ __forceinline__ unsigned short f2bf(float f) {
    unsigned u = __builtin_bit_cast(unsigned, f);
    u = (u + 0x7FFFu + ((u >> 16) & 1u)) >> 16;
    return (unsigned short)u;
}
__device__ __forceinline__ void split2(float v, unsigned short& h, unsigned short& l) {
    h = f2bf(v);
    float hf = __builtin_bit_cast(float, ((unsigned)h) << 16);
    l = f2bf(v - hf);
}
__device__ __forceinline__ float bf2f(unsigned short u) {
    return __builtin_bit_cast(float, ((unsigned)u) << 16);
}

// ---- split-store helper: one (kc, n-group) of a weight split job ----
__device__ __forceinline__ void split_store(
    const float* __restrict__ W, unsigned short* __restrict__ oh,
    unsigned short* __restrict__ ol, int N, int Npad, int coff,
    int rowoff, int perm, int kc, int n) {
    int src = perm ? ((n & 3) * 1024 + (n >> 2)) : n;
    short8 vh, vl;
    #pragma unroll
    for (int j = 0; j < 8; ++j) {
        float v = (src < N) ? W[(size_t)(rowoff + kc * 8 + j) * N + src] : 0.f;
        unsigned short h, l; split2(v, h, l);
        vh[j] = (short)h; vl[j] = (short)l;
    }
    size_t o = ((size_t)kc * Npad + coff + n) * 8;
    *(short8*)(oh + o) = vh; *(short8*)(ol + o) = vl;
}

// ---- mega prologue kernel: all weight splits + bias_perm + embed in ONE launch ----
// ranges: j0 [0,128) W_enc ; j1 [128,384) W_dec->wbig@0 ; j2 [384,640) W_fbeta->wbig@512 ;
// j3 [640,2688) W_hh->wbig@1024 perm ; j4 [2688,4736) W_ih[0:1024]->wih1 perm ;
// j5 [4736,5760) W_ih[1024:1536]->wih2 perm ; j6 [5760,5776) bias_perm ;
// j7 [5776,7312) embed gather
__global__ __launch_bounds__(256) void megasplit_kernel(
    const float* __restrict__ W_enc, unsigned short* __restrict__ wenc_h, unsigned short* __restrict__ wenc_l,
    const float* __restrict__ W_dec, const float* __restrict__ W_fbeta, const float* __restrict__ W_hh,
    unsigned short* __restrict__ wbig_h, unsigned short* __restrict__ wbig_l,
    const float* __restrict__ W_ih,
    unsigned short* __restrict__ wih1_h, unsigned short* __restrict__ wih1_l,
    unsigned short* __restrict__ wih2_h, unsigned short* __restrict__ wih2_l,
    const float* __restrict__ b_ih, const float* __restrict__ b_hh, float* __restrict__ biasp,
    const int* __restrict__ captions, const float* __restrict__ table, float* __restrict__ emb_f) {
    int bid = blockIdx.x, tid = threadIdx.x;
    if (bid < 128) {                     // j0: W_enc [512][512] -> wenc
        int local = bid, xb = local & 1, kc = local >> 1;
        split_store(W_enc, wenc_h, wenc_l, 512, 512, 0, 0, 0, kc, xb * 256 + tid);
    } else if (bid < 384) {              // j1: W_dec [1024][512] -> wbig@0
        int local = bid - 128, xb = local & 1, kc = local >> 1;
        split_store(W_dec, wbig_h, wbig_l, 512, 5120, 0, 0, 0, kc, xb * 256 + tid);
    } else if (bid < 640) {              // j2: W_fbeta [1024][512] -> wbig@512
        int local = bid - 384, xb = local & 1, kc = local >> 1;
        split_store(W_fbeta, wbig_h, wbig_l, 512, 5120, 512, 0, 0, kc, xb * 256 + tid);
    } else if (bid < 2688) {             // j3: W_hh [1024][4096] -> wbig@1024, perm
        int local = bid - 640, xb = local & 15, kc = local >> 4;
        split_store(W_hh, wbig_h, wbig_l, 4096, 5120, 1024, 0, 1, kc, xb * 256 + tid);
    } else if (bid < 4736) {             // j4: W_ih rows 0-1023 -> wih1, perm
        int local = bid - 2688, xb = local & 15, kc = local >> 4;
        split_store(W_ih, wih1_h, wih1_l, 4096, 4096, 0, 0, 1, kc, xb * 256 + tid);
    } else if (bid < 5760) {             // j5: W_ih rows 1024-1535 -> wih2, perm
        int local = bid - 4736, xb = local & 15, kc = local >> 4;
        split_store(W_ih, wih2_h, wih2_l, 4096, 4096, 0, 1024, 1, kc, xb * 256 + tid);
    } else if (bid < 5776) {             // j6: permuted combined bias
        int n = (bid - 5760) * 256 + tid;
        int src = (n & 3) * 1024 + (n >> 2);
        biasp[n] = b_ih[src] + b_hh[src];
    } else {                             // j7: embed gather (fp32 rows, r = t*64+b)
        int local = bid - 5776;
        int t = local >> 6, b = local & 63;
        int tok = captions[b * 25 + t];
        const float4* src = (const float4*)(table + (size_t)tok * ED);
        float4* dst = (float4*)(emb_f + ((size_t)t * BB + b) * ED);
        dst[tid] = src[tid];
    }
}

// ---- enc -> bf16 copy (context-phase operand) ----
__global__ __launch_bounds__(256) void enc2bf16_kernel(
    const float* __restrict__ enc, unsigned short* __restrict__ encb) {
    size_t idx = ((size_t)blockIdx.x * 256 + threadIdx.x) * 8;
    float4 v0 = *(const float4*)(enc + idx);
    float4 v1 = *(const float4*)(enc + idx + 4);
    short8 o;
    o[0] = (short)f2bf(v0.x); o[1] = (short)f2bf(v0.y);
    o[2] = (short)f2bf(v0.z); o[3] = (short)f2bf(v0.w);
    o[4] = (short)f2bf(v1.x); o[5] = (short)f2bf(v1.y);
    o[6] = (short)f2bf(v1.z); o[7] = (short)f2bf(v1.w);
    *(short8*)(encb + idx) = o;
}

// ---- wfc split (epilogue only) ----
__global__ __launch_bounds__(256) void split_w_kernel(
    const float* __restrict__ W, unsigned short* __restrict__ oh,
    unsigned short* __restrict__ ol, int N, int Npad, int coff,
    int Nlaunch, int rowoff, int perm) {
    int n = blockIdx.x * 256 + threadIdx.x;
    if (n >= Nlaunch) return;
    split_store(W, oh, ol, N, Npad, coff, rowoff, perm, blockIdx.y, n);
}

__global__ __launch_bounds__(512) void mean_kernel(const float* __restrict__ enc,
                                                   float* __restrict__ mf) {
    int b = blockIdx.x; int e = threadIdx.x;
    const float* base = enc + (size_t)b * PP * ENCD + e;
    float s = 0.f;
    #pragma unroll 4
    for (int p = 0; p < PP; ++p) s += base[(size_t)p * ENCD];
    mf[b * ENCD + e] = s * (1.f / PP);
}

__global__ __launch_bounds__(256) void init_hc_kernel(
    const float* __restrict__ mf,
    const float* __restrict__ Wh, const float* __restrict__ bh,
    const float* __restrict__ Wc, const float* __restrict__ bc,
    unsigned short* __restrict__ hc_h, unsigned short* __restrict__ hc_l,
    float* __restrict__ c0) {
    int b = blockIdx.x;
    int isC = blockIdx.y;
    const float* W    = isC ? Wc : Wh;
    const float* bias = isC ? bc : bh;
    __shared__ float smf[ENCD];
    for (int i = threadIdx.x; i < ENCD; i += 256) smf[i] = mf[b * ENCD + i];
    __syncthreads();
    #pragma unroll
    for (int jj = 0; jj < 4; ++jj) {
        int j = threadIdx.x + jj * 256;
        float acc = bias[j];
        for (int k = 0; k < ENCD; ++k) acc += smf[k] * W[(size_t)k * HD + j];
        if (isC) c0[b * HD + j] = acc;
        else {
            unsigned short h, l; split2(acc, h, l);
            size_t o = ((size_t)(j >> 3) * 64 + b) * 8 + (j & 7);
            hc_h[o] = h; hc_l[o] = l;
        }
    }
}

// ---- big MFMA GEMM, A fp32 row-major (in-kernel split), B chunked hi/lo, prefetched ----
__global__ __launch_bounds__(256) void mfma_gemm_bigf(
    const float* __restrict__ Ap,
    const unsigned short* __restrict__ Bh, const unsigned short* __restrict__ Bl,
    const float* __restrict__ bias, float* __restrict__ C,
    int N, int Npad, int K, int Mtiles, int Ntiles, int inner_m) {
    __shared__ __align__(16) short lds[32768];
    short* Ahs = lds;
    short* Als = lds + 8192;
    short* Bhs = lds + 16384;
    short* Bls = lds + 24576;
    int tid = threadIdx.x, lane = tid & 63, w = tid >> 6;
    int nwg = Mtiles * Ntiles;
    int orig = blockIdx.x;
    int q = nwg >> 3, r = nwg & 7;
    int xcd = orig & 7;
    int basew = (xcd < r) ? xcd * (q + 1) : r * (q + 1) + (xcd - r) * q;
    int wg = basew + (orig >> 3);
    int mt, nt;
    if (inner_m) { mt = wg % Mtiles; nt = wg / Mtiles; }
    else         { nt = wg % Ntiles; mt = wg / Ntiles; }
    int m0 = mt * 128, n0 = nt * 128;
    int wr = w >> 1, wc = w & 1;
    f32x4 acc[4][4];
    #pragma unroll
    for (int i = 0; i < 4; ++i)
        #pragma unroll
        for (int j = 0; j < 4; ++j) acc[i][j] = (f32x4){0.f, 0.f, 0.f, 0.f};
    int nsteps = K >> 6;
    float4 va[8];
    short8 rb[2][4];
    auto load_step = [&](int s) {
        int k0 = s * 64, kc0 = s * 8;
        #pragma unroll
        for (int it = 0; it < 8; ++it) {
            int idx = it * 256 + tid; int m = idx >> 4, k4 = idx & 15;
            va[it] = *(const float4*)(Ap + (size_t)(m0 + m) * K + k0 + k4 * 4);
        }
        #pragma unroll
        for (int it = 0; it < 4; ++it) {
            int g = w * 4 + it; int kcl = g >> 1; int rb0 = (g & 1) * 64;
            size_t gb = ((size_t)(kc0 + kcl) * Npad + n0 + rb0 + lane) * 8;
            rb[0][it] = *(const short8*)(Bh + gb);
            rb[1][it] = *(const short8*)(Bl + gb);
        }
    };
    load_step(0);
    for (int s = 0; s < nsteps; ++s) {
        __syncthreads();
        #pragma unroll
        for (int it = 0; it < 8; ++it) {
            int idx = it * 256 + tid; int m = idx >> 4, k4 = idx & 15;
            int kc = k4 >> 1, jh = (k4 & 1) * 4;
            float vv[4] = {va[it].x, va[it].y, va[it].z, va[it].w};
            short4v hv, lv;
            #pragma unroll
            for (int qq = 0; qq < 4; ++qq) {
                unsigned short h, l; split2(vv[qq], h, l);
                hv[qq] = (short)h; lv[qq] = (short)l;
            }
            int o = kc * 1024 + ((m ^ kc) << 3) + jh;
            *(short4v*)(Ahs + o) = hv;
            *(short4v*)(Als + o) = lv;
        }
        #pragma unroll
        for (int it = 0; it < 4; ++it) {
            int g = w * 4 + it; int kcl = g >> 1; int rb0 = (g & 1) * 64;
            int o = (kcl * 128 + rb0 + lane) * 8;
            *(short8*)(Bhs + o) = rb[0][it];
            *(short8*)(Bls + o) = rb[1][it];
        }
        __syncthreads();
        if (s + 1 < nsteps) load_step(s + 1);
        #pragma unroll
        for (int ks = 0; ks < 2; ++ks) {
            int kq = ks * 4 + (lane >> 4);
            short8 afh[4], afl[4], bfh[4], bfl[4];
            #pragma unroll
            for (int mi = 0; mi < 4; ++mi) {
                int row = wr * 64 + mi * 16 + (lane & 15);
                int o = kq * 1024 + ((row ^ kq) << 3);
                afh[mi] = *(const short8*)(Ahs + o);
                afl[mi] = *(const short8*)(Als + o);
            }
            #pragma unroll
            for (int ni = 0; ni < 4; ++ni) {
                int o = (kq * 128 + wc * 64 + ni * 16 + (lane & 15)) * 8;
                bfh[ni] = *(const short8*)(Bhs + o);
                bfl[ni] = *(const short8*)(Bls + o);
            }
            #pragma unroll
            for (int mi = 0; mi < 4; ++mi)
                #pragma unroll
                for (int ni = 0; ni < 4; ++ni) {
                    acc[mi][ni] = __builtin_amdgcn_mfma_f32_16x16x32_bf16(afh[mi], bfh[ni], acc[mi][ni], 0, 0, 0);
                    acc[mi][ni] = __builtin_amdgcn_mfma_f32_16x16x32_bf16(afh[mi], bfl[ni], acc[mi][ni], 0, 0, 0);
                    acc[mi][ni] = __builtin_amdgcn_mfma_f32_16x16x32_bf16(afl[mi], bfh[ni], acc[mi][ni], 0, 0, 0);
                }
        }
    }
    #pragma unroll
    for (int mi = 0; mi < 4; ++mi) {
        int rrow = m0 + wr * 64 + mi * 16 + ((lane >> 4) << 2);
        #pragma unroll
        for (int ni = 0; ni < 4; ++ni) {
            int c = n0 + wc * 64 + ni * 16 + (lane & 15);
            if (c < N) {
                float bv = bias ? bias[c] : 0.f;
                #pragma unroll
                for (int qq = 0; qq < 4; ++qq)
                    C[(size_t)(rrow + qq) * N + c] = acc[mi][ni][qq] + bv;
            }
        }
    }
}

// ---- phase-1: adg = h @ [W_dec|W_fbeta|Whh(perm)] — zero-barrier direct-fragment GEMM ----
__global__ __launch_bounds__(256) void hgemm_direct(
    const unsigned short* __restrict__ Ah, const unsigned short* __restrict__ Al,
    const unsigned short* __restrict__ Bh, const unsigned short* __restrict__ Bl,
    float* __restrict__ out) {
    int tid = threadIdx.x, lane = tid & 63, w = tid >> 6;
    int n0 = blockIdx.x * 128 + w * 32;
    int kc0 = blockIdx.y * 16;
    out += (size_t)blockIdx.y * 64 * 5120;
    f32x4 acc[4][2];
    #pragma unroll
    for (int i = 0; i < 4; ++i)
        #pragma unroll
        for (int j = 0; j < 2; ++j) acc[i][j] = (f32x4){0.f, 0.f, 0.f, 0.f};
    #pragma unroll
    for (int s = 0; s < 4; ++s) {
        int kc = kc0 + s * 4 + (lane >> 4);
        short8 afh[4], afl[4], bfh[2], bfl[2];
        #pragma unroll
        for (int mi = 0; mi < 4; ++mi) {
            size_t o = ((size_t)kc * 64 + mi * 16 + (lane & 15)) * 8;
            afh[mi] = *(const short8*)(Ah + o);
            afl[mi] = *(const short8*)(Al + o);
        }
        #pragma unroll
        for (int ni = 0; ni < 2; ++ni) {
            size_t o = ((size_t)kc * 5120 + n0 + ni * 16 + (lane & 15)) * 8;
            bfh[ni] = *(const short8*)(Bh + o);
            bfl[ni] = *(const short8*)(Bl + o);
        }
        #pragma unroll
        for (int mi = 0; mi < 4; ++mi)
            #pragma unroll
            for (int ni = 0; ni < 2; ++ni) {
                acc[mi][ni] = __builtin_amdgcn_mfma_f32_16x16x32_bf16(afh[mi], bfh[ni], acc[mi][ni], 0, 0, 0);
                acc[mi][ni] = __builtin_amdgcn_mfma_f32_16x16x32_bf16(afh[mi], bfl[ni], acc[mi][ni], 0, 0, 0);
                acc[mi][ni] = __builtin_amdgcn_mfma_f32_16x16x32_bf16(afl[mi], bfh[ni], acc[mi][ni], 0, 0, 0);
            }
    }
    #pragma unroll
    for (int mi = 0; mi < 4; ++mi) {
        int rrow = mi * 16 + ((lane >> 4) << 2);
        #pragma unroll
        for (int ni = 0; ni < 2; ++ni) {
            int c = n0 + ni * 16 + (lane & 15);
            #pragma unroll
            for (int qq = 0; qq < 4; ++qq)
                out[(size_t)(rrow + qq) * 5120 + c] = acc[mi][ni][qq];
        }
    }
}

// ---- fused per-step attention (energy fp32 att_enc; context bf16 enc) ----
__global__ __launch_bounds__(1024) void attn_ctx_kernel(
    const float* __restrict__ att_enc, const float* __restrict__ adg,
    const float* __restrict__ b_dec, const float* __restrict__ Wfull,
    const unsigned short* __restrict__ encb, const float* __restrict__ b_fbeta,
    float* __restrict__ alpha_out, unsigned short* __restrict__ x2h,
    unsigned short* __restrict__ x2l, int t) {
    int b = blockIdx.x; int tid = threadIdx.x;
    __shared__ float sdec[AD], sw[AD], sgate[AD], sal[256], sE[256], red[256];
    __shared__ float sctx[2][AD];
    if (tid < AD) {
        float s = b_dec[tid];
        #pragma unroll
        for (int ks = 0; ks < 8; ++ks) s += adg[((size_t)ks * BB + b) * 5120 + tid];
        sdec[tid] = s;
        sw[tid] = Wfull[tid];
    } else {
        int e = tid - AD;
        float s = b_fbeta[e];
        #pragma unroll
        for (int ks = 0; ks < 8; ++ks) s += adg[((size_t)ks * BB + b) * 5120 + 512 + e];
        sgate[e] = s;
    }
    __syncthreads();
    int w = tid >> 6, lane = tid & 63;
    float4 sd0 = *(const float4*)&sdec[lane * 8];
    float4 sd1 = *(const float4*)&sdec[lane * 8 + 4];
    float4 sw0 = *(const float4*)&sw[lane * 8];
    float4 sw1 = *(const float4*)&sw[lane * 8 + 4];
    for (int p = w; p < PP; p += 16) {
        const float* row = att_enc + ((size_t)b * PP + p) * AD + lane * 8;
        float4 v0 = *(const float4*)row;
        float4 v1 = *(const float4*)(row + 4);
        float part = fmaxf(v0.x + sd0.x, 0.f) * sw0.x + fmaxf(v0.y + sd0.y, 0.f) * sw0.y +
                     fmaxf(v0.z + sd0.z, 0.f) * sw0.z + fmaxf(v0.w + sd0.w, 0.f) * sw0.w +
                     fmaxf(v1.x + sd1.x, 0.f) * sw1.x + fmaxf(v1.y + sd1.y, 0.f) * sw1.y +
                     fmaxf(v1.z + sd1.z, 0.f) * sw1.z + fmaxf(v1.w + sd1.w, 0.f) * sw1.w;
        #pragma unroll
        for (int off = 32; off > 0; off >>= 1) part += __shfl_down(part, off, 64);
        if (lane == 0) sE[p] = part;
    }
    __syncthreads();
    float myE = (tid < PP) ? sE[tid] : -1e30f;
    if (tid < 256) red[tid] = myE;
    __syncthreads();
    for (int s = 128; s > 0; s >>= 1) {
        if (tid < s) red[tid] = fmaxf(red[tid], red[tid + s]);
        __syncthreads();
    }
    float mx = red[0];
    __syncthreads();
    float ex = (tid < PP) ? __expf(myE - mx) : 0.f;
    if (tid < 256) red[tid] = ex;
    __syncthreads();
    for (int s = 128; s > 0; s >>= 1) {
        if (tid < s) red[tid] += red[tid + s];
        __syncthreads();
    }
    if (tid < PP) {
        float al = ex * (1.f / red[0]);
        sal[tid] = al;
        alpha_out[((size_t)b * TT + t) * PP + tid] = al;
    }
    __syncthreads();
    int e = tid & 511, half = tid >> 9;
    const unsigned short* basep = encb + (size_t)b * PP * ENCD + e;
    float s2 = 0.f;
    #pragma unroll 2
    for (int p = half * 98; p < half * 98 + 98; ++p)
        s2 += sal[p] * bf2f(basep[(size_t)p * ENCD]);
    sctx[half][e] = s2;
    __syncthreads();
    if (tid < AD) {
        float ctx = sctx[0][tid] + sctx[1][tid];
        float gate = sigf(sgate[tid]);
        unsigned short h, l; split2(gate * ctx, h, l);
        size_t o = ((size_t)(tid >> 3) * 64 + b) * 8 + (tid & 7);
        x2h[o] = h; x2l[o] = l;
    }
}

// ---- phase-3: gates = x2 @ Wih2(perm) [K=512, cross-wave split] + partials -> LSTM ----
__global__ __launch_bounds__(256) void gates_lstm2(
    const unsigned short* __restrict__ Ah, const unsigned short* __restrict__ Al,
    const unsigned short* __restrict__ Bh, const unsigned short* __restrict__ Bl,
    const float* __restrict__ pregates, const float* __restrict__ adg,
    float* __restrict__ c, unsigned short* __restrict__ ho_h,
    unsigned short* __restrict__ ho_l, float* __restrict__ h_all, int t) {
    __shared__ float gl[4][64][33];
    int tid = threadIdx.x, lane = tid & 63, w = tid >> 6;
    int n0 = blockIdx.x * 32;
    f32x4 acc[4][2];
    #pragma unroll
    for (int i = 0; i < 4; ++i)
        #pragma unroll
        for (int j = 0; j < 2; ++j) acc[i][j] = (f32x4){0.f, 0.f, 0.f, 0.f};
    #pragma unroll
    for (int s = 0; s < 4; ++s) {
        int kc = w * 16 + s * 4 + (lane >> 4);
        short8 afh[4], afl[4], bfh[2], bfl[2];
        #pragma unroll
        for (int mi = 0; mi < 4; ++mi) {
            size_t o = ((size_t)kc * 64 + mi * 16 + (lane & 15)) * 8;
            afh[mi] = *(const short8*)(Ah + o);
            afl[mi] = *(const short8*)(Al + o);
        }
        #pragma unroll
        for (int ni = 0; ni < 2; ++ni) {
            size_t o = ((size_t)kc * 4096 + n0 + ni * 16 + (lane & 15)) * 8;
            bfh[ni] = *(const short8*)(Bh + o);
            bfl[ni] = *(const short8*)(Bl + o);
        }
        #pragma unroll
        for (int mi = 0; mi < 4; ++mi)
            #pragma unroll
            for (int ni = 0; ni < 2; ++ni) {
                acc[mi][ni] = __builtin_amdgcn_mfma_f32_16x16x32_bf16(afh[mi], bfh[ni], acc[mi][ni], 0, 0, 0);
                acc[mi][ni] = __builtin_amdgcn_mfma_f32_16x16x32_bf16(afh[mi], bfl[ni], acc[mi][ni], 0, 0, 0);
                acc[mi][ni] = __builtin_amdgcn_mfma_f32_16x16x32_bf16(afl[mi], bfh[ni], acc[mi][ni], 0, 0, 0);
            }
    }
    #pragma unroll
    for (int mi = 0; mi < 4; ++mi) {
        int rrow = mi * 16 + ((lane >> 4) << 2);
        #pragma unroll
        for (int ni = 0; ni < 2; ++ni) {
            int cl = ni * 16 + (lane & 15);
            #pragma unroll
            for (int qq = 0; qq < 4; ++qq)
                gl[w][rrow + qq][cl] = acc[mi][ni][qq];
        }
    }
    __syncthreads();
    #pragma unroll
    for (int i = 0; i < 2; ++i) {
        int idx = tid + i * 256;
        int b = idx >> 3, jl = idx & 7;
        float g4[4];
        #pragma unroll
        for (int qq = 0; qq < 4; ++qq)
            g4[qq] = gl[0][b][4 * jl + qq] + gl[1][b][4 * jl + qq] +
                     gl[2][b][4 * jl + qq] + gl[3][b][4 * jl + qq];
        {
            float4 pv = *(const float4*)&pregates[((size_t)(t * 64 + b)) * 4096 + n0 + 4 * jl];
            g4[0] += pv.x; g4[1] += pv.y; g4[2] += pv.z; g4[3] += pv.w;
        }
        #pragma unroll
        for (int ks = 0; ks < 8; ++ks) {
            float4 av = *(const float4*)&adg[((size_t)ks * BB + b) * 5120 + 1024 + n0 + 4 * jl];
            g4[0] += av.x; g4[1] += av.y; g4[2] += av.z; g4[3] += av.w;
        }
        int j = (n0 >> 2) + jl;
        float cn = sigf(g4[1]) * c[b * HD + j] + sigf(g4[0]) * tanhf(g4[2]);
        c[b * HD + j] = cn;
        float hn = sigf(g4[3]) * tanhf(cn);
        unsigned short h, l; split2(hn, h, l);
        size_t o1 = ((size_t)(j >> 3) * 64 + b) * 8 + (j & 7);
        ho_h[o1] = h; ho_l[o1] = l;
        h_all[((size_t)b * TT + t) * HD + j] = hn;
    }
}

extern "C" void kernel_launch(void* const* d_in, const int* in_sizes, int n_in,
                              void* d_out, int out_size, void* d_ws, size_t ws_size,
                              hipStream_t stream) {
    const float* enc      = (const float*)d_in[0];
    const int*   captions = (const int*)d_in[1];
    const float* W_enc    = (const float*)d_in[3];
    const float* b_enc    = (const float*)d_in[4];
    const float* W_dec    = (const float*)d_in[5];
    const float* b_dec    = (const float*)d_in[6];
    const float* W_full   = (const float*)d_in[7];
    const float* table    = (const float*)d_in[9];
    const float* W_ih     = (const float*)d_in[10];   // [1536][4096]
    const float* b_ih     = (const float*)d_in[11];
    const float* W_hh     = (const float*)d_in[12];   // [1024][4096]
    const float* b_hh     = (const float*)d_in[13];
    const float* W_init_h = (const float*)d_in[14];
    const float* b_init_h = (const float*)d_in[15];
    const float* W_init_c = (const float*)d_in[16];
    const float* b_init_c = (const float*)d_in[17];
    const float* W_fbeta  = (const float*)d_in[18];
    const float* b_fbeta  = (const float*)d_in[19];
    const float* W_fc     = (const float*)d_in[20];
    const float* b_fc     = (const float*)d_in[21];

    float* preds  = (float*)d_out;                         // [64][24][20000]
    float* alphas = (float*)d_out + (size_t)BB * TT * VD;  // [64][24][196]

    // ---- workspace carve (R8-proven footprint ~116 MB). Front region dead after
    //      loop -> wfc overlays it. encb aliases wih1 (dead after pregates GEMM). ----
    char* base = (char*)d_ws;
    size_t off = 0;
    auto take = [&](size_t b) { void* r = (void*)(base + off); off += (b + 255) & ~(size_t)255; return r; };
    float* att_enc = (float*)take((size_t)12544 * 512 * 4);                      // 25.7 MB
    unsigned short* wbig_h = (unsigned short*)take((size_t)128 * 5120 * 8 * 2);  // 10.5 x2
    unsigned short* wbig_l = (unsigned short*)take((size_t)128 * 5120 * 8 * 2);
    unsigned short* wih1_h = (unsigned short*)take((size_t)128 * 4096 * 8 * 2);  // 8.4 x2
    unsigned short* wih1_l = (unsigned short*)take((size_t)128 * 4096 * 8 * 2);
    unsigned short* encb   = (unsigned short*)wih1_h;   // 12.85 MB <= 16.8 MB, written after pregates GEMM
    unsigned short* wih2_h = (unsigned short*)take((size_t)64 * 4096 * 8 * 2);   // 4.2 x2
    unsigned short* wih2_l = (unsigned short*)take((size_t)64 * 4096 * 8 * 2);
    unsigned short* wenc_h = (unsigned short*)take((size_t)64 * 512 * 8 * 2);    // 0.52 x2
    unsigned short* wenc_l = (unsigned short*)take((size_t)64 * 512 * 8 * 2);
    float* pregates = (float*)take((size_t)TT * BB * 4096 * 4);                  // 25.2
    float* adg      = (float*)take((size_t)8 * BB * 5120 * 4);                   // 10.5
    float* emb_f    = adg;   // aliases adg (dead before loop)
    float* biasp    = (float*)take((size_t)4096 * 4);
    // wfc overlays [0, off): written AFTER the loop
    unsigned short* wfc_h = (unsigned short*)(base);
    unsigned short* wfc_l = (unsigned short*)(base + (size_t)128 * VPAD * 8 * 2);
    // persistent (live across wfc write):
    float* c_buf = (float*)take((size_t)BB * HD * 4);
    float* mf    = (float*)take((size_t)BB * ENCD * 4);
    unsigned short* axh_h0 = (unsigned short*)take((size_t)192 * 64 * 8 * 2);
    unsigned short* axh_l0 = (unsigned short*)take((size_t)192 * 64 * 8 * 2);
    unsigned short* axh_h1 = (unsigned short*)take((size_t)192 * 64 * 8 * 2);
    unsigned short* axh_l1 = (unsigned short*)take((size_t)192 * 64 * 8 * 2);
    float* h_all = (float*)take((size_t)TT * BB * HD * 4);                       // 6.3

    // ---- prologue (6 dispatches) ----
    megasplit_kernel<<<7312, 256, 0, stream>>>(
        W_enc, wenc_h, wenc_l, W_dec, W_fbeta, W_hh, wbig_h, wbig_l,
        W_ih, wih1_h, wih1_l, wih2_h, wih2_l,
        b_ih, b_hh, biasp, captions, table, emb_f);
    mean_kernel<<<BB, 512, 0, stream>>>(enc, mf);
    init_hc_kernel<<<dim3(BB, 2), 256, 0, stream>>>(mf, W_init_h, b_init_h, W_init_c, b_init_c,
                                                    axh_h0 + HOFF, axh_l0 + HOFF, c_buf);
    // att_enc = enc @ W_enc + b_enc : M=12544 N=512 K=512
    mfma_gemm_bigf<<<392, 256, 0, stream>>>(enc, wenc_h, wenc_l, b_enc, att_enc,
                                            512, 512, 512, 98, 4, 0);
    // pregates = emb @ W_ih[0:1024] (perm cols) + (b_ih+b_hh) perm : M=1536 N=4096 K=1024
    mfma_gemm_bigf<<<384, 256, 0, stream>>>(emb_f, wih1_h, wih1_l, biasp, pregates,
                                            4096, 4096, 1024, 12, 32, 1);
    // enc -> bf16 (context operand); aliases wih1 which is now dead
    enc2bf16_kernel<<<3136, 256, 0, stream>>>(enc, encb);

    // ---- step loop: 3 dispatches/step ----
    {
        unsigned short* ah[2] = {axh_h0, axh_h1};
        unsigned short* al[2] = {axh_l0, axh_l1};
        for (int t = 0; t < TT; ++t) {
            int par = t & 1;
            hgemm_direct<<<dim3(40, 8), 256, 0, stream>>>(
                ah[par] + HOFF, al[par] + HOFF, wbig_h, wbig_l, adg);
            attn_ctx_kernel<<<BB, 1024, 0, stream>>>(att_enc, adg, b_dec, W_full, encb,
                                                     b_fbeta, alphas, ah[par], al[par], t);
            gates_lstm2<<<128, 256, 0, stream>>>(
                ah[par], al[par], wih2_h, wih2_l, pregates, adg, c_buf,
                ah[1 - par] + HOFF, al[1 - par] + HOFF, h_all, t);
        }
    }

    // ---- epilogue ----
    split_w_kernel<<<dim3(79, 128), 256, 0, stream>>>(W_fc, wfc_h, wfc_l, VD, VPAD, 0, VPAD, 0, 0);
    mfma_gemm_bigf<<<1884, 256, 0, stream>>>(h_all, wfc_h, wfc_l, b_fc, preds,
                                             VD, VPAD, 1024, 12, 157, 1);
}